// Round 1
// 442.240 us; speedup vs baseline: 1.3387x; 1.3387x over previous
//
#include <hip/hip_runtime.h>
#include <hip/hip_bf16.h>
#include <math.h>

// Problem dims (fixed by reference):
//   thing_map   [1, 80, 128, 256]  fp32
//   kernel_space[1,256, 128, 256]  fp32
//   embeddings  [1,256, 256, 512]  fp32
// Outputs (concat, fp32): thing_masks [1,50,256,512] | scores [1,50] | cats [1,50]

constexpr int C   = 80;
constexpr int H   = 128;
constexpr int W   = 256;
constexpr int HW  = H * W;            // 32768
constexpr int CHW = C * HW;           // 2,621,440
constexpr int D   = 256;
constexpr int NPIX = 256 * 512;       // 131072
constexpr int K   = 50;
constexpr int KP  = 52;               // padded k count (13 float4 per d-row)
constexpr int NBINS = 4096;
constexpr int MAXCAND = 8192;
constexpr int SEL_CAP = 4096;
constexpr int MASK_ELEMS = K * NPIX;  // 6,553,600

// ws layout (units: 4-byte words)
constexpr int OFF_CENTERS = 0;                      // float[CHW]
constexpr int OFF_HIST    = CHW;                    // int[NBINS]
constexpr int OFF_CUTBIN  = OFF_HIST + NBINS;       // int
constexpr int OFF_CCOUNT  = OFF_CUTBIN + 1;         // int
constexpr int OFF_CVAL    = OFF_CCOUNT + 1;         // float[MAXCAND]
constexpr int OFF_CIDX    = OFF_CVAL + MAXCAND;     // int[MAXCAND]
constexpr int OFF_TSCORE  = OFF_CIDX + MAXCAND;     // float[K]
constexpr int OFF_TSPAT   = OFF_TSCORE + K;         // int[K]
constexpr int OFF_TCAT    = OFF_TSPAT + K;          // int[K]
constexpr int OFF_A       = OFF_TCAT + K;           // float[D*KP], TRANSPOSED At[d][52]
constexpr int OFF_FNUM    = OFF_A + KP * D;         // float[K]
constexpr int OFF_FDEN    = OFF_FNUM + K;           // float[K]
constexpr int OFF_PEAKV   = OFF_FDEN + K;           // float[CHW] (optional, ws_size-gated)

// compile-safe repetition for the 13 float4 accumulators
#define REP13(X) X(0) X(1) X(2) X(3) X(4) X(5) X(6) X(7) X(8) X(9) X(10) X(11) X(12)

__device__ __forceinline__ float sigmoidf(float x) {
    return 1.0f / (1.0f + expf(-x));
}

// ------------- centers = 0.5*(sigmoid(x) + avgpool3x3(sigmoid(x))) -------------
// block 0 also zero-inits the atomically-accumulated ws regions (used by LATER launches)
__global__ void centers_kernel(const float* __restrict__ x, float* __restrict__ ws) {
    if (blockIdx.x == 0) {
        int* wsi = (int*)ws;
        for (int i = threadIdx.x; i < NBINS; i += 256) wsi[OFF_HIST + i] = 0;
        if (threadIdx.x < K) { ws[OFF_FNUM + threadIdx.x] = 0.0f; ws[OFF_FDEN + threadIdx.x] = 0.0f; }
        if (threadIdx.x == 0) wsi[OFF_CCOUNT] = 0;
    }
    int idx = blockIdx.x * 256 + threadIdx.x;
    if (idx >= CHW) return;
    int w = idx & (W - 1);
    int h = (idx >> 8) & (H - 1);
    int cbase = idx & ~(HW - 1);   // c * HW
    float s0 = sigmoidf(x[idx]);
    float sum = 0.0f;
    #pragma unroll
    for (int dh = -1; dh <= 1; dh++) {
        int hh = h + dh;
        if ((unsigned)hh >= (unsigned)H) continue;   // zero-pad for avg
        #pragma unroll
        for (int dw = -1; dw <= 1; dw++) {
            int ww = w + dw;
            if ((unsigned)ww >= (unsigned)W) continue;
            sum += sigmoidf(x[cbase + (hh << 8) + ww]);
        }
    }
    ws[OFF_CENTERS + idx] = 0.5f * (s0 + sum / 9.0f);
}

// peak value at idx: centers[idx] if it equals the 3x3 max (-inf pad), else -1
__device__ __forceinline__ float peak_value(const float* cen, int idx) {
    int w = idx & (W - 1);
    int h = (idx >> 8) & (H - 1);
    int cbase = idx & ~(HW - 1);
    float c0 = cen[idx];
    float m = c0;
    #pragma unroll
    for (int dh = -1; dh <= 1; dh++) {
        int hh = h + dh;
        if ((unsigned)hh >= (unsigned)H) continue;
        #pragma unroll
        for (int dw = -1; dw <= 1; dw++) {
            int ww = w + dw;
            if ((unsigned)ww >= (unsigned)W) continue;
            m = fmaxf(m, cen[cbase + (hh << 8) + ww]);
        }
    }
    return (c0 == m) ? c0 : -1.0f;
}

__device__ __forceinline__ int value_bin(float v) {
    int b = (int)(v * (float)NBINS);
    return b > NBINS - 1 ? NBINS - 1 : b;
}

// ---------------- histogram of peak values (values in (0,1)) ----------------
__global__ void hist_kernel(float* ws, float* peakv) {
    int idx = blockIdx.x * 256 + threadIdx.x;
    if (idx >= CHW) return;
    const float* cen = ws + OFF_CENTERS;
    float v = peak_value(cen, idx);
    if (peakv) peakv[idx] = v;
    if (v >= 0.0f) {
        atomicAdd((int*)ws + OFF_HIST + value_bin(v), 1);
    }
}

// ---------------- suffix-scan histogram to find the rank-50 cutoff bin --------
__global__ void scan_kernel(float* ws) {
    __shared__ int chunk[256];
    const int* hist = (const int*)ws + OFF_HIST;
    int t = threadIdx.x;
    int s = 0;
    #pragma unroll
    for (int b = t * 16; b < t * 16 + 16; b++) s += hist[b];
    chunk[t] = s;
    __syncthreads();
    if (t == 0) {
        int cum = 0, cutbin = 0;
        bool found = false;
        for (int ch = 255; ch >= 0 && !found; ch--) {
            if (cum + chunk[ch] >= K) {
                for (int b = ch * 16 + 15; b >= ch * 16; b--) {
                    cum += hist[b];
                    if (cum >= K) { cutbin = b; found = true; break; }
                }
            } else {
                cum += chunk[ch];
            }
        }
        ((int*)ws)[OFF_CUTBIN] = found ? cutbin : 0;
    }
}

// ---------------- gather all candidates with bin >= cutoff ----------------
__global__ void gather_kernel(float* ws, const float* peakv) {
    int idx = blockIdx.x * 256 + threadIdx.x;
    if (idx >= CHW) return;
    float v = peakv ? peakv[idx] : peak_value(ws + OFF_CENTERS, idx);
    if (v >= 0.0f) {
        int cutbin = ((const int*)ws)[OFF_CUTBIN];
        if (value_bin(v) >= cutbin) {
            int pos = atomicAdd((int*)ws + OFF_CCOUNT, 1);
            if (pos < MAXCAND) {
                ws[OFF_CVAL + pos] = v;
                ((int*)ws)[OFF_CIDX + pos] = idx;
            }
        }
    }
}

// ---------------- single-wave top-50 selection (value desc, index asc) --------
__global__ void select_kernel(float* ws) {
    __shared__ float sv[SEL_CAP];
    __shared__ int   si[SEL_CAP];
    __shared__ unsigned smask[MAXCAND / 32];   // 1 = already selected
    const float* cval = ws + OFF_CVAL;
    const int*   cidx = (const int*)ws + OFF_CIDX;
    int n = ((const int*)ws)[OFF_CCOUNT];
    if (n > MAXCAND) n = MAXCAND;
    int t = threadIdx.x;   // 64 threads = one wave

    int cap = n < SEL_CAP ? n : SEL_CAP;
    for (int q = t; q < cap; q += 64) { sv[q] = cval[q]; si[q] = cidx[q]; }
    for (int q = t; q < MAXCAND / 32; q += 64) smask[q] = 0u;
    __syncthreads();

    for (int j = 0; j < K; j++) {
        float bv = -1e30f; int bi = 0x7fffffff; int bp = -1;
        for (int q = t; q < n; q += 64) {
            if (smask[q >> 5] & (1u << (q & 31))) continue;
            float v; int id;
            if (q < SEL_CAP) { v = sv[q]; id = si[q]; }
            else             { v = cval[q]; id = cidx[q]; }
            if (v > bv || (v == bv && id < bi)) { bv = v; bi = id; bp = q; }
        }
        #pragma unroll
        for (int m = 1; m < 64; m <<= 1) {
            float ov = __shfl_xor(bv, m);
            int   oi = __shfl_xor(bi, m);
            int   op = __shfl_xor(bp, m);
            if (ov > bv || (ov == bv && oi < bi)) { bv = ov; bi = oi; bp = op; }
        }
        if (t == 0) {
            float score = (bp >= 0) ? bv : 0.0f;
            int   idx   = (bp >= 0) ? bi : 0;
            ws[OFF_TSCORE + j] = score;
            ((int*)ws)[OFF_TSPAT + j] = idx & (HW - 1);
            ((int*)ws)[OFF_TCAT + j]  = idx >> 15;        // idx / HW
            if (bp >= 0) smask[bp >> 5] |= (1u << (bp & 31));
        }
        __syncthreads();
    }
}

// ---------------- gather kernel vectors, TRANSPOSED: At[d][k] = ksp[d][spatial_k]
// grid = KP (52): k columns 50,51 are zero padding (d_ws is poisoned every call).
// Row stride 52 floats = 208 B = 13 aligned float4s (OFF_A is 16B-aligned).
__global__ void gatherA_kernel(const float* __restrict__ ksp, float* __restrict__ ws) {
    int k = blockIdx.x;     // 0..51
    int d = threadIdx.x;    // 256
    float v = 0.0f;
    if (k < K) {
        int sp = ((const int*)ws)[OFF_TSPAT + k];
        v = ksp[d * HW + sp];
    }
    ws[OFF_A + d * KP + k] = v;
}

// ---------------- mask GEMM v2: out[k][n] = sigmoid(At[:,k] . emb[:,n]) -------
// 1 thread = 1 pixel, all 52 k's in 13 named float4 accumulators (fully static
// indexing -> no scratch spill). Each pixel is owned by exactly one thread, so
// emb streams from HBM exactly once, coalesced 256B/wave, no LDS at all.
// A is read per d-row as 13 contiguous float4s at a genuinely uniform address
// (loop counter x kernel arg) -> scalar/L1-cached loads; each 4-row group of
// A loads feeds 208 FMAs (vs 13 loads per 13 FMAs before).
// 512 blocks x 4 waves = 8 waves/CU; 4-row e-prefetch hides HBM latency under
// ~416 cycles of FMA issue per iteration.
#define FMAROW(i) { const float4 a_ = Arow[i]; \
    c##i.x = fmaf(e, a_.x, c##i.x); \
    c##i.y = fmaf(e, a_.y, c##i.y); \
    c##i.z = fmaf(e, a_.z, c##i.z); \
    c##i.w = fmaf(e, a_.w, c##i.w); }

__global__ __launch_bounds__(256) void gemm_kernel(
        const float* __restrict__ emb,
        const float* __restrict__ At,    // [D][KP], rows 16B-aligned
        float* __restrict__ out) {
    const int n = blockIdx.x * 256 + threadIdx.x;
    const float4* __restrict__ Af = (const float4*)At;   // 13 float4 per d-row

#define DECLC(i) float4 c##i = make_float4(0.0f, 0.0f, 0.0f, 0.0f);
    REP13(DECLC)
#undef DECLC

    const float* __restrict__ ep = emb + n;
    float cur0 = ep[(size_t)0 * NPIX];
    float cur1 = ep[(size_t)1 * NPIX];
    float cur2 = ep[(size_t)2 * NPIX];
    float cur3 = ep[(size_t)3 * NPIX];

    for (int d = 0; d < D - 4; d += 4) {
        // prefetch next 4 e-values (in flight under this iteration's 208 FMAs)
        const float* q = ep + (size_t)(d + 4) * NPIX;
        float nxt0 = q[0];
        float nxt1 = q[(size_t)1 * NPIX];
        float nxt2 = q[(size_t)2 * NPIX];
        float nxt3 = q[(size_t)3 * NPIX];
        { const float4* Arow = Af + (d + 0) * 13; const float e = cur0; REP13(FMAROW) }
        { const float4* Arow = Af + (d + 1) * 13; const float e = cur1; REP13(FMAROW) }
        { const float4* Arow = Af + (d + 2) * 13; const float e = cur2; REP13(FMAROW) }
        { const float4* Arow = Af + (d + 3) * 13; const float e = cur3; REP13(FMAROW) }
        cur0 = nxt0; cur1 = nxt1; cur2 = nxt2; cur3 = nxt3;
    }
    // tail: rows D-4 .. D-1
    { const float4* Arow = Af + (D - 4) * 13; const float e = cur0; REP13(FMAROW) }
    { const float4* Arow = Af + (D - 3) * 13; const float e = cur1; REP13(FMAROW) }
    { const float4* Arow = Af + (D - 2) * 13; const float e = cur2; REP13(FMAROW) }
    { const float4* Arow = Af + (D - 1) * 13; const float e = cur3; REP13(FMAROW) }

    float* op = out + n;
#define EPI(i) \
    if (4*(i)+0 < K) op[(size_t)(4*(i)+0) * NPIX] = 1.0f/(1.0f+expf(-c##i.x)); \
    if (4*(i)+1 < K) op[(size_t)(4*(i)+1) * NPIX] = 1.0f/(1.0f+expf(-c##i.y)); \
    if (4*(i)+2 < K) op[(size_t)(4*(i)+2) * NPIX] = 1.0f/(1.0f+expf(-c##i.z)); \
    if (4*(i)+3 < K) op[(size_t)(4*(i)+3) * NPIX] = 1.0f/(1.0f+expf(-c##i.w));
    REP13(EPI)
#undef EPI
}

// ---------------- rescore: fnum[k] = sum(v where v>0.4), fden[k] = count ------
// Streams masks back from d_out (26 MB ~ 5 us). grid = (K, 16); each y-slice
// covers 2048 float4 = 8 reads/thread at stride 256 (exact cover).
__global__ __launch_bounds__(256) void rescore_kernel(
        const float* __restrict__ masks,
        float* __restrict__ fnum,
        float* __restrict__ fden) {
    const int k = blockIdx.x;
    const float4* mk = (const float4*)(masks + (size_t)k * NPIX);
    float a = 0.0f; float b = 0.0f;
    int base = blockIdx.y * 2048 + threadIdx.x;   // float4 units
    #pragma unroll
    for (int r = 0; r < 8; r++) {
        float4 v = mk[base + r * 256];
        if (v.x > 0.4f) { a += v.x; b += 1.0f; }
        if (v.y > 0.4f) { a += v.y; b += 1.0f; }
        if (v.z > 0.4f) { a += v.z; b += 1.0f; }
        if (v.w > 0.4f) { a += v.w; b += 1.0f; }
    }
    a += __shfl_xor(a, 1);  b += __shfl_xor(b, 1);
    a += __shfl_xor(a, 2);  b += __shfl_xor(b, 2);
    a += __shfl_xor(a, 4);  b += __shfl_xor(b, 4);
    a += __shfl_xor(a, 8);  b += __shfl_xor(b, 8);
    a += __shfl_xor(a, 16); b += __shfl_xor(b, 16);
    a += __shfl_xor(a, 32); b += __shfl_xor(b, 32);
    __shared__ float sa[4], sb[4];
    int wave = threadIdx.x >> 6;
    if ((threadIdx.x & 63) == 0) { sa[wave] = a; sb[wave] = b; }
    __syncthreads();
    if (threadIdx.x == 0) {
        atomicAdd(&fnum[k], sa[0] + sa[1] + sa[2] + sa[3]);
        atomicAdd(&fden[k], sb[0] + sb[1] + sb[2] + sb[3]);
    }
}

// ---------------- finalize: scores & cats ----------------
__global__ void finalize_kernel(const float* __restrict__ ws, float* __restrict__ out) {
    int j = threadIdx.x;
    if (j < K) {
        float s = ws[OFF_TSCORE + j];
        float num = ws[OFF_FNUM + j];
        float den = ws[OFF_FDEN + j];
        float factor = num / fmaxf(den, 1e-8f);
        float valid = (s > 0.1f) ? 1.0f : 0.0f;
        out[MASK_ELEMS + j]     = s * factor * valid;
        out[MASK_ELEMS + K + j] = (float)(((const int*)ws)[OFF_TCAT + j]);
    }
}

extern "C" void kernel_launch(void* const* d_in, const int* in_sizes, int n_in,
                              void* d_out, int out_size, void* d_ws, size_t ws_size,
                              hipStream_t stream) {
    const float* thing_map = (const float*)d_in[0];
    const float* ksp       = (const float*)d_in[1];
    const float* emb       = (const float*)d_in[2];
    float* out = (float*)d_out;
    float* ws  = (float*)d_ws;

    bool have_peakv = ws_size >= (size_t)(OFF_PEAKV + CHW) * sizeof(float);
    float* peakv = have_peakv ? (ws + OFF_PEAKV) : nullptr;

    centers_kernel<<<CHW / 256, 256, 0, stream>>>(thing_map, ws);
    hist_kernel<<<CHW / 256, 256, 0, stream>>>(ws, peakv);
    scan_kernel<<<1, 256, 0, stream>>>(ws);
    gather_kernel<<<CHW / 256, 256, 0, stream>>>(ws, peakv);
    select_kernel<<<1, 64, 0, stream>>>(ws);
    gatherA_kernel<<<KP, D, 0, stream>>>(ksp, ws);
    gemm_kernel<<<NPIX / 256, 256, 0, stream>>>(emb, ws + OFF_A, out);
    rescore_kernel<<<dim3(K, 16), 256, 0, stream>>>(out, ws + OFF_FNUM, ws + OFF_FDEN);
    finalize_kernel<<<1, 64, 0, stream>>>(ws, out);
}